// Round 13
// baseline (298.423 us; speedup 1.0000x reference)
//
#include <hip/hip_runtime.h>
#include <hip/hip_bf16.h>
#include <hip/hip_fp16.h>

#define B_    128
#define T_    200
#define C_    40
#define NCODE 2000
#define DAUX  16
#define E_    128
#define H_    256
#define G4    512          // 4*E

typedef _Float16 half8 __attribute__((ext_vector_type(8)));
typedef float    floatx4 __attribute__((ext_vector_type(4)));

__device__ __forceinline__ float sigmoid_fast(float x) {
    return __fdividef(1.f, 1.f + __expf(-x));
}
__device__ __forceinline__ float tanh_fast(float x) {
    x = fminf(15.f, fmaxf(-15.f, x));
    float e = __expf(2.f * x);
    return __fdividef(e - 1.f, e + 1.f);
}

// ---------------------------------------------------------------------------
// Kernel 1: front-end (unchanged).
// ---------------------------------------------------------------------------
__global__ __launch_bounds__(128) void fe_kernel(
    const int* __restrict__ code, const float* __restrict__ aux,
    const float* __restrict__ W_lin, const float* __restrict__ b_lin,
    const int* __restrict__ length, float* __restrict__ x)
{
    const int cell = blockIdx.x;          // b*T_ + t
    const int e = threadIdx.x;            // 0..127
    const int b = cell / T_;
    const int t = cell - b * T_;

    if (t >= length[b]) {                 // dead cell: zero-fill (uniform exit)
        x[(size_t)cell * E_ + e] = 0.f;
        return;
    }

    __shared__ int codes[C_];
    __shared__ int keep[C_];

    if (e < C_) {
        int cj = code[cell * C_ + e];
        codes[e] = cj;
        keep[e] = (cj != 0);
    }
    __syncthreads();
    for (int p = e; p < C_ * C_; p += 128) {
        int i  = p / C_;
        int jj = p - i * C_;
        if (i < jj && codes[i] == codes[jj]) keep[jj] = 0;
    }
    __syncthreads();

    float acc = b_lin[e];
    #pragma unroll 8
    for (int j = 0; j < C_; ++j) {
        int cj = codes[j];
        float w = (float)keep[j];
        int row = (cj > 0) ? (cj - 1) : 0;
        acc = fmaf(w, W_lin[row * E_ + e], acc);
    }
    const float* arow = aux + (size_t)cell * DAUX;
    #pragma unroll
    for (int d = 0; d < DAUX; ++d)
        acc = fmaf(arow[d], W_lin[(NCODE + d) * E_ + e], acc);

    x[(size_t)cell * E_ + e] = fmaxf(acc, 0.f);
}

// ---------------------------------------------------------------------------
// Kernel 2: z_pre = x @ W_x + b_lstm (unchanged).
// ---------------------------------------------------------------------------
__global__ __launch_bounds__(256) void gemm_kernel(
    const float* __restrict__ x, const float* __restrict__ Wx,
    const float* __restrict__ bl, const int* __restrict__ length,
    float* __restrict__ z)
{
    const int m0 = blockIdx.x * 64;
    const int n0 = blockIdx.y * 64;

    {
        int b_first = m0 / T_;
        int b_last  = (m0 + 63) / T_;
        if (b_first == b_last && (m0 - b_first * T_) >= length[b_first])
            return;
    }

    __shared__ float4 As[64][32];
    __shared__ float4 Bt[64][32];

    const int tid = threadIdx.x;

    const float4* x4 = (const float4*)x;
    #pragma unroll
    for (int i = 0; i < 8; ++i) {
        int idx = tid + i * 256;
        int r = idx >> 5, c = idx & 31;
        As[r][c ^ (r & 7)] = x4[(size_t)(m0 + r) * 32 + c];
    }
    #pragma unroll
    for (int i = 0; i < 32; ++i) {
        int idx = tid + i * 256;
        int k = idx >> 6, n = idx & 63;
        ((float*)&Bt[n][(k >> 2) ^ (n & 7)])[k & 3] = Wx[k * G4 + n0 + n];
    }
    __syncthreads();

    const int tn = tid & 15;
    const int tm = tid >> 4;
    float acc[4][4] = {};

    #pragma unroll
    for (int k4 = 0; k4 < 32; ++k4) {
        float4 a[4], bb[4];
        #pragma unroll
        for (int i = 0; i < 4; ++i) {
            int r = 4 * tm + i;
            a[i] = As[r][k4 ^ (r & 7)];
        }
        #pragma unroll
        for (int c = 0; c < 4; ++c)
            bb[c] = Bt[tn + 16 * c][k4 ^ (tn & 7)];
        #pragma unroll
        for (int i = 0; i < 4; ++i)
            #pragma unroll
            for (int c = 0; c < 4; ++c) {
                acc[i][c] = fmaf(a[i].x, bb[c].x, acc[i][c]);
                acc[i][c] = fmaf(a[i].y, bb[c].y, acc[i][c]);
                acc[i][c] = fmaf(a[i].z, bb[c].z, acc[i][c]);
                acc[i][c] = fmaf(a[i].w, bb[c].w, acc[i][c]);
            }
    }

    #pragma unroll
    for (int i = 0; i < 4; ++i) {
        int row = m0 + 4 * tm + i;
        #pragma unroll
        for (int c = 0; c < 4; ++c) {
            int col = n0 + tn + 16 * c;
            z[(size_t)row * G4 + col] = acc[i][c] + bl[col];
        }
    }
}

// ---------------------------------------------------------------------------
// Kernel 3: LSTM via MFMA, RAW-BARRIER step loop.
// R12 diagnosis: __syncthreads() emits `s_waitcnt vmcnt(0) lgkmcnt(0)` before
// s_barrier -> every step DRAINED the depth-2 z prefetch to completion,
// putting ~900 cy of L2/L3 latency on the per-step critical path (measured
// 1530 cy/step vs ~600 cy chain model; depth-2 prefetch gained only 5%).
// Fix (AITER/HK counted-wait pattern): in-loop sync = s_waitcnt lgkmcnt(0)
// (makes the h ds_write visible; does NOT touch vmcnt) + raw s_barrier +
// sched_barrier(0) (rule #18: stop the scheduler hoisting the next step's
// ds_read/MFMA above the wait). The z loads now genuinely stay in flight
// across barriers for ~2 steps before their compiler-inserted vmcnt wait.
// Also: pair accumulators (2x 2-deep MFMA chains + 1 scalar add) instead of
// one 4-deep chain -> ~2 MFMA latencies off the chain.
// ---------------------------------------------------------------------------
__global__ __launch_bounds__(512, 2) void lstm_kernel(
    const float* __restrict__ z_pre, const float* __restrict__ Wh,
    const int* __restrict__ length, float* __restrict__ last_h)
{
    const int b   = blockIdx.x;
    const int tid = threadIdx.x;
    const int w   = tid >> 6;       // wave 0..7
    const int l   = tid & 63;       // lane
    const int col = l & 15;         // n within tile
    const int kg  = l >> 4;         // k-group 0..3

    __shared__ __align__(16) _Float16 hbuf[2][E_];

    // ---- loop-invariant B fragments: bf[gate][kslice], 8 fp16 each ----
    half8 bf[4][4];
    #pragma unroll
    for (int g = 0; g < 4; ++g) {
        const int ncol = g * E_ + w * 16 + col;
        #pragma unroll
        for (int s4 = 0; s4 < 4; ++s4) {
            const int k0 = s4 * 32 + kg * 8;
            half8 hb;
            #pragma unroll
            for (int e = 0; e < 8; ++e)
                hb[e] = (_Float16)Wh[(size_t)(k0 + e) * G4 + ncol];
            bf[g][s4] = hb;
        }
    }

    const int len = length[b];
    const float* zp = z_pre + (size_t)b * T_ * G4 + w * 16 + col;

    if (tid < E_) hbuf[0][tid] = (_Float16)0.f;
    float c_st = 0.f;                         // meaningful in kg==0 lanes

    // depth-2 pending sets (z_pre already contains b_lstm)
    const int t1 = (1 < len) ? 1 : 0;
    float zA0 = zp[0], zA1 = zp[E_], zA2 = zp[2 * E_], zA3 = zp[3 * E_];
    float zB0 = zp[(size_t)t1 * G4], zB1 = zp[(size_t)t1 * G4 + E_],
          zB2 = zp[(size_t)t1 * G4 + 2 * E_], zB3 = zp[(size_t)t1 * G4 + 3 * E_];
    __syncthreads();   // one full drain before the loop is fine

#define LSTM_STEP(T, ZR0, ZR1, ZR2, ZR3, RBUF, WBUF)                          \
    {                                                                          \
        /* consume pending set (vmcnt wait for loads issued at T-2) */         \
        float c0 = ZR0, c1 = ZR1, c2 = ZR2, c3 = ZR3;                          \
        /* re-issue this set for step T+2; stays in flight across barriers */  \
        {                                                                      \
            int tf = ((T) + 2 < len) ? (T) + 2 : len - 1;                      \
            const float* zf = zp + (size_t)tf * G4;                            \
            ZR0 = zf[0]; ZR1 = zf[E_]; ZR2 = zf[2 * E_]; ZR3 = zf[3 * E_];     \
        }                                                                      \
        half8 af0 = *(const half8*)&hbuf[RBUF][0 * 32 + kg * 8];               \
        half8 af1 = *(const half8*)&hbuf[RBUF][1 * 32 + kg * 8];               \
        half8 af2 = *(const half8*)&hbuf[RBUF][2 * 32 + kg * 8];               \
        half8 af3 = *(const half8*)&hbuf[RBUF][3 * 32 + kg * 8];               \
        floatx4 a0 = {c0, 0.f, 0.f, 0.f}, e0 = {0.f, 0.f, 0.f, 0.f};           \
        floatx4 a1 = {c1, 0.f, 0.f, 0.f}, e1 = {0.f, 0.f, 0.f, 0.f};           \
        floatx4 a2 = {c2, 0.f, 0.f, 0.f}, e2 = {0.f, 0.f, 0.f, 0.f};           \
        floatx4 a3 = {c3, 0.f, 0.f, 0.f}, e3 = {0.f, 0.f, 0.f, 0.f};           \
        a0 = __builtin_amdgcn_mfma_f32_16x16x32_f16(af0, bf[0][0], a0, 0, 0, 0); \
        a0 = __builtin_amdgcn_mfma_f32_16x16x32_f16(af1, bf[0][1], a0, 0, 0, 0); \
        e0 = __builtin_amdgcn_mfma_f32_16x16x32_f16(af2, bf[0][2], e0, 0, 0, 0); \
        e0 = __builtin_amdgcn_mfma_f32_16x16x32_f16(af3, bf[0][3], e0, 0, 0, 0); \
        a1 = __builtin_amdgcn_mfma_f32_16x16x32_f16(af0, bf[1][0], a1, 0, 0, 0); \
        a1 = __builtin_amdgcn_mfma_f32_16x16x32_f16(af1, bf[1][1], a1, 0, 0, 0); \
        e1 = __builtin_amdgcn_mfma_f32_16x16x32_f16(af2, bf[1][2], e1, 0, 0, 0); \
        e1 = __builtin_amdgcn_mfma_f32_16x16x32_f16(af3, bf[1][3], e1, 0, 0, 0); \
        a2 = __builtin_amdgcn_mfma_f32_16x16x32_f16(af0, bf[2][0], a2, 0, 0, 0); \
        a2 = __builtin_amdgcn_mfma_f32_16x16x32_f16(af1, bf[2][1], a2, 0, 0, 0); \
        e2 = __builtin_amdgcn_mfma_f32_16x16x32_f16(af2, bf[2][2], e2, 0, 0, 0); \
        e2 = __builtin_amdgcn_mfma_f32_16x16x32_f16(af3, bf[2][3], e2, 0, 0, 0); \
        a3 = __builtin_amdgcn_mfma_f32_16x16x32_f16(af0, bf[3][0], a3, 0, 0, 0); \
        a3 = __builtin_amdgcn_mfma_f32_16x16x32_f16(af1, bf[3][1], a3, 0, 0, 0); \
        e3 = __builtin_amdgcn_mfma_f32_16x16x32_f16(af2, bf[3][2], e3, 0, 0, 0); \
        e3 = __builtin_amdgcn_mfma_f32_16x16x32_f16(af3, bf[3][3], e3, 0, 0, 0); \
        float ig = sigmoid_fast(a0[0] + e0[0]);                                \
        float fg = sigmoid_fast(a1[0] + e1[0]);                                \
        float gg = tanh_fast(a2[0] + e2[0]);                                   \
        float og = sigmoid_fast(a3[0] + e3[0]);                                \
        c_st = fg * c_st + ig * gg;                                            \
        float h = og * tanh_fast(c_st);                                        \
        if (kg == 0) {                                                         \
            hbuf[WBUF][w * 16 + col] = (_Float16)h;                            \
            if ((T) == len - 1) last_h[b * E_ + w * 16 + col] = h;             \
        }                                                                      \
        /* DS-only wait (h write visible) + raw barrier: z loads NOT drained */\
        asm volatile("s_waitcnt lgkmcnt(0)" ::: "memory");                     \
        __builtin_amdgcn_s_barrier();                                          \
        __builtin_amdgcn_sched_barrier(0);                                     \
    }

    for (int s = 0; s < len; s += 2) {
        LSTM_STEP(s, zA0, zA1, zA2, zA3, 0, 1)
        if (s + 1 >= len) break;
        LSTM_STEP(s + 1, zB0, zB1, zB2, zB3, 1, 0)
    }
#undef LSTM_STEP
}

// ---------------------------------------------------------------------------
// Kernel 4: MLP head + L2 normalize (unchanged).
// ---------------------------------------------------------------------------
__global__ __launch_bounds__(256) void mlp_kernel(
    const float* __restrict__ last_h, const float* __restrict__ W0,
    const float* __restrict__ b0, const float* __restrict__ W1,
    const float* __restrict__ b1, float* __restrict__ out)
{
    const int b = blockIdx.x;
    const int j = threadIdx.x;    // 0..255

    __shared__ float lrow[E_];
    __shared__ float hid[H_];
    __shared__ float red[H_];

    if (j < E_) lrow[j] = last_h[b * E_ + j];
    __syncthreads();

    float a = b0[j];
    #pragma unroll 8
    for (int k = 0; k < E_; ++k)
        a = fmaf(lrow[k], W0[k * H_ + j], a);
    hid[j] = fmaxf(a, 0.f);
    __syncthreads();

    float f = b1[j];
    #pragma unroll 8
    for (int k = 0; k < H_; ++k)
        f = fmaf(hid[k], W1[k * H_ + j], f);

    red[j] = f * f;
    __syncthreads();
    #pragma unroll
    for (int s = 128; s > 0; s >>= 1) {
        if (j < s) red[j] += red[j + s];
        __syncthreads();
    }
    out[(size_t)b * H_ + j] = f / sqrtf(red[0]);
}

// ---------------------------------------------------------------------------
extern "C" void kernel_launch(void* const* d_in, const int* in_sizes, int n_in,
                              void* d_out, int out_size, void* d_ws, size_t ws_size,
                              hipStream_t stream)
{
    const int*   code  = (const int*)  d_in[0];
    const float* aux   = (const float*)d_in[1];
    const int*   length= (const int*)  d_in[2];
    // d_in[3] = is_training (ignored; inference path)
    const float* W_lin = (const float*)d_in[4];
    const float* b_lin = (const float*)d_in[5];
    const float* W_x   = (const float*)d_in[6];
    const float* W_h   = (const float*)d_in[7];
    const float* b_lstm= (const float*)d_in[8];
    const float* W0    = (const float*)d_in[9];
    const float* b0    = (const float*)d_in[10];
    const float* W1    = (const float*)d_in[11];
    const float* b1    = (const float*)d_in[12];
    float* out = (float*)d_out;

    // workspace layout
    char* ws = (char*)d_ws;
    float* x      = (float*)ws;                                   // 25600*128 f32
    float* z_pre  = (float*)(ws + (size_t)B_ * T_ * E_ * 4);      // 25600*512 f32
    float* last_h = (float*)(ws + (size_t)B_ * T_ * E_ * 4
                                + (size_t)B_ * T_ * G4 * 4);      // 128*128 f32

    fe_kernel<<<B_ * T_, 128, 0, stream>>>(code, aux, W_lin, b_lin, length, x);
    gemm_kernel<<<dim3((B_ * T_) / 64, G4 / 64), 256, 0, stream>>>(x, W_x, b_lstm, length, z_pre);
    lstm_kernel<<<B_, 512, 0, stream>>>(z_pre, W_h, length, last_h);
    mlp_kernel<<<B_, H_, 0, stream>>>(last_h, W0, b0, W1, b1, out);
}